// Round 5
// baseline (352.660 us; speedup 1.0000x reference)
//
#include <hip/hip_runtime.h>
#include <cstddef>
#include <cstdint>

// Problem constants
static constexpr int M_ROWS  = 32768;   // B*T
static constexpr int D_INK   = 1024;
static constexpr int D_HID   = 512;
static constexpr int D_CODE_ = 256;
static constexpr int N_CODES_= 128;

static constexpr float TAU_GAP = 0.02f;   // ambiguity threshold (error bound ~1e-3 -> 20x margin)

using bf16x8 = __attribute__((ext_vector_type(8))) __bf16;
using f32x4  = __attribute__((ext_vector_type(4))) float;

// ---------------------------------------------------------------------------
// direct global->LDS DMA, 16 B per lane (dest = wave-uniform base + lane*16)
// ---------------------------------------------------------------------------
__device__ __forceinline__ void dma16(const void* g, void* l) {
    __builtin_amdgcn_global_load_lds(
        (const __attribute__((address_space(1))) void*)g,
        (__attribute__((address_space(3))) void*)l, 16, 0, 0);
}

__device__ __forceinline__ void stage_pair_dma(const __bf16* __restrict__ hi,
                                               const __bf16* __restrict__ lo,
                                               __bf16* shi, __bf16* slo,
                                               int w, int lane, int row0, int stride, int k0)
{
    #pragma unroll
    for (int ii = 0; ii < 2; ++ii) {
        const int I  = 2 * w + ii;          // 0..7
        const int f  = I * 64 + lane;       // frag 0..511
        const int rc = f & 127;
        const int kq = f >> 7;
        const size_t go = (size_t)(row0 + rc) * stride + k0 + kq * 8;
        dma16(hi + go, shi + (size_t)I * 512);
        dma16(lo + go, slo + (size_t)I * 512);
    }
}

// one BK=32 compute step: 4x4 fragment tile per wave, 3-product hi/lo split
__device__ __forceinline__ void mfma_tile(const __bf16* sAh, const __bf16* sAl,
                                          const __bf16* sBh, const __bf16* sBl,
                                          int wm, int wn, int kq, int lm,
                                          f32x4 (&acc)[4][4])
{
    bf16x8 ah[4], al[4];
    #pragma unroll
    for (int fm = 0; fm < 4; ++fm) {
        const int fA = kq * 128 + wm * 64 + fm * 16 + lm;
        ah[fm] = *(const bf16x8*)(sAh + fA * 8);
        al[fm] = *(const bf16x8*)(sAl + fA * 8);
    }
    #pragma unroll
    for (int fn = 0; fn < 4; ++fn) {
        const int fB = kq * 128 + wn * 64 + fn * 16 + lm;
        const bf16x8 bh = *(const bf16x8*)(sBh + fB * 8);
        const bf16x8 bl = *(const bf16x8*)(sBl + fB * 8);
        #pragma unroll
        for (int fm = 0; fm < 4; ++fm) {
            acc[fm][fn] = __builtin_amdgcn_mfma_f32_16x16x32_bf16(ah[fm], bh, acc[fm][fn], 0, 0, 0);
            acc[fm][fn] = __builtin_amdgcn_mfma_f32_16x16x32_bf16(al[fm], bh, acc[fm][fn], 0, 0, 0);
            acc[fm][fn] = __builtin_amdgcn_mfma_f32_16x16x32_bf16(ah[fm], bl, acc[fm][fn], 0, 0, 0);
        }
    }
}

// ---------------------------------------------------------------------------
// prep: split codebook to hi/lo bf16, per-code norms, zero accumulators.
// ---------------------------------------------------------------------------
__global__ __launch_bounds__(256)
void prep_cb_kernel(const float* __restrict__ cb, __bf16* __restrict__ cbhi,
                    __bf16* __restrict__ cblo, float* __restrict__ cbnorm,
                    float* __restrict__ accum, int* __restrict__ cnt)
{
    const int j = blockIdx.x;
    const int t = threadIdx.x;
    const float v = cb[j * D_CODE_ + t];
    const __bf16 hb = (__bf16)v;
    cbhi[j * D_CODE_ + t] = hb;
    cblo[j * D_CODE_ + t] = (__bf16)(v - (float)hb);

    __shared__ float sr[256];
    sr[t] = v * v;
    __syncthreads();
    for (int s = 128; s >= 1; s >>= 1) {
        if (t < s) sr[t] += sr[t + s];
        __syncthreads();
    }
    if (t == 0) cbnorm[j] = sr[0];
    if (j == 0 && t < 2) accum[t] = 0.0f;
    if (j == 0 && t == 2) *cnt = 0;
}

// ---------------------------------------------------------------------------
// splitT: W [K][N] fp32 -> WT_hi/WT_lo [N][K] bf16, via LDS-tiled transpose
// (coalesced loads AND contiguous 128-B output stores). 64x64 tiles.
// ---------------------------------------------------------------------------
__global__ __launch_bounds__(256)
void splitT_kernel(const float* __restrict__ W, __bf16* __restrict__ Thi,
                   __bf16* __restrict__ Tlo, int Kd, int Nd)
{
    __shared__ __bf16 sh[64][66];
    __shared__ __bf16 sl[64][66];
    const int t = threadIdx.x;
    const int k0 = blockIdx.x * 64, n0 = blockIdx.y * 64;
    {
        const int nl = t & 63, kr = t >> 6;
        #pragma unroll
        for (int r = 0; r < 16; ++r) {
            const int kl = kr * 16 + r;
            const float v = W[(size_t)(k0 + kl) * Nd + n0 + nl];
            const __bf16 hb = (__bf16)v;
            sh[kl][nl] = hb;
            sl[kl][nl] = (__bf16)(v - (float)hb);
        }
    }
    __syncthreads();
    {
        const int kl = t & 63, nr = t >> 6;
        #pragma unroll
        for (int r = 0; r < 16; ++r) {
            const int nl = nr * 16 + r;
            Thi[(size_t)(n0 + nl) * Kd + k0 + kl] = sh[kl][nl];
            Tlo[(size_t)(n0 + nl) * Kd + k0 + kl] = sl[kl][nl];
        }
    }
}

// ---------------------------------------------------------------------------
// GEMM1: h(hi/lo) = relu(x @ W1 + b1).
// All-register staging (NO global_load_lds) + raw s_barrier (lgkmcnt-only
// drain -> global prefetches survive the barrier). x prefetched 4 steps
// ahead (HBM ~900cy), B(W1T, L2-resident) 2 steps ahead.
// ---------------------------------------------------------------------------
#define G1_XLOAD(S, T_) do { \
    *(float4*)&(S)[0]  = *(const float4*)(xp0 + (T_) * 32); \
    *(float4*)&(S)[4]  = *(const float4*)(xp0 + (T_) * 32 + 4); \
    *(float4*)&(S)[8]  = *(const float4*)(xp1 + (T_) * 32); \
    *(float4*)&(S)[12] = *(const float4*)(xp1 + (T_) * 32 + 4); \
  } while (0)

#define G1_BLOAD(Bs, T_) do { \
    (Bs)[0] = *(const bf16x8*)(bph0 + (T_) * 32); \
    (Bs)[1] = *(const bf16x8*)(bpl0 + (T_) * 32); \
    (Bs)[2] = *(const bf16x8*)(bph1 + (T_) * 32); \
    (Bs)[3] = *(const bf16x8*)(bpl1 + (T_) * 32); \
  } while (0)

#define G1_AWRITE(S, NXT) do { \
    bf16x8 h8, l8; \
    _Pragma("unroll") \
    for (int j = 0; j < 8; ++j) { const float v = (S)[j]; const __bf16 hb = (__bf16)v; h8[j] = hb; l8[j] = (__bf16)(v - (float)hb); } \
    *(bf16x8*)(&lds[NXT][0][0] + f0 * 8) = h8; *(bf16x8*)(&lds[NXT][1][0] + f0 * 8) = l8; \
    _Pragma("unroll") \
    for (int j = 0; j < 8; ++j) { const float v = (S)[8 + j]; const __bf16 hb = (__bf16)v; h8[j] = hb; l8[j] = (__bf16)(v - (float)hb); } \
    *(bf16x8*)(&lds[NXT][0][0] + f1 * 8) = h8; *(bf16x8*)(&lds[NXT][1][0] + f1 * 8) = l8; \
  } while (0)

#define G1_BWRITE(Bs, NXT) do { \
    *(bf16x8*)(&lds[NXT][2][0] + f0 * 8) = (Bs)[0]; \
    *(bf16x8*)(&lds[NXT][3][0] + f0 * 8) = (Bs)[1]; \
    *(bf16x8*)(&lds[NXT][2][0] + f1 * 8) = (Bs)[2]; \
    *(bf16x8*)(&lds[NXT][3][0] + f1 * 8) = (Bs)[3]; \
  } while (0)

#define G1_STEP(T_, CUR, NXT, XI, XC, BI, BC) do { \
    if ((T_) + 4 < 32) G1_XLOAD(XI, (T_) + 4); \
    if ((T_) + 2 < 32) G1_BLOAD(BI, (T_) + 2); \
    mfma_tile(&lds[CUR][0][0], &lds[CUR][1][0], &lds[CUR][2][0], &lds[CUR][3][0], wm, wn, kq, lm, acc); \
    if ((T_) + 1 < 32) { G1_AWRITE(XC, NXT); G1_BWRITE(BC, NXT); } \
    asm volatile("s_waitcnt lgkmcnt(0)" ::: "memory"); \
    __builtin_amdgcn_s_barrier(); \
    __builtin_amdgcn_sched_barrier(0); \
  } while (0)

__global__ __launch_bounds__(256, 2)
void gemm1_kernel(const float* __restrict__ X,
                  const __bf16* __restrict__ BThi, const __bf16* __restrict__ BTlo,
                  const float* __restrict__ bias,
                  __bf16* __restrict__ Chi, __bf16* __restrict__ Clo)
{
    __shared__ __bf16 lds[2][4][4096];     // 64 KB -> 2 blocks/CU

    const int tid  = threadIdx.x;
    const int lane = tid & 63;
    const int w    = tid >> 6;
    const int wm = w >> 1, wn = w & 1;
    const int kq = lane >> 4, lm = lane & 15;
    const int m0 = blockIdx.x * 128, n0 = blockIdx.y * 128;

    f32x4 acc[4][4] = {};

    // frag ownership: f0 = tid (kg 0/1), f1 = tid + 256 (kg 2/3); same row.
    const int f0 = tid, f1 = tid + 256;
    const float*  xp0  = X    + (size_t)(m0 + (f0 & 127)) * D_INK + (f0 >> 7) * 8;
    const float*  xp1  = X    + (size_t)(m0 + (f1 & 127)) * D_INK + (f1 >> 7) * 8;
    const __bf16* bph0 = BThi + (size_t)(n0 + (f0 & 127)) * D_INK + (f0 >> 7) * 8;
    const __bf16* bpl0 = BTlo + (size_t)(n0 + (f0 & 127)) * D_INK + (f0 >> 7) * 8;
    const __bf16* bph1 = BThi + (size_t)(n0 + (f1 & 127)) * D_INK + (f1 >> 7) * 8;
    const __bf16* bpl1 = BTlo + (size_t)(n0 + (f1 & 127)) * D_INK + (f1 >> 7) * 8;

    float  xs0[16], xs1[16], xs2[16], xs3[16];
    bf16x8 bs0[4], bs1[4];

    // prologue: fill buf0 with step 0; prefetch x[1..3], B[1]
    G1_XLOAD(xs1, 1);
    G1_XLOAD(xs2, 2);
    G1_XLOAD(xs3, 3);
    G1_BLOAD(bs1, 1);
    G1_XLOAD(xs0, 0);
    G1_BLOAD(bs0, 0);
    G1_AWRITE(xs0, 0);
    G1_BWRITE(bs0, 0);
    asm volatile("s_waitcnt lgkmcnt(0)" ::: "memory");
    __builtin_amdgcn_s_barrier();
    __builtin_amdgcn_sched_barrier(0);

    for (int tb = 0; tb < 32; tb += 4) {
        G1_STEP(tb + 0, 0, 1, xs0, xs1, bs0, bs1);
        G1_STEP(tb + 1, 1, 0, xs1, xs2, bs1, bs0);
        G1_STEP(tb + 2, 0, 1, xs2, xs3, bs0, bs1);
        G1_STEP(tb + 3, 1, 0, xs3, xs0, bs1, bs0);
    }

    // epilogue: relu + hi/lo split store (C/D: col = lane&15, row = kq*4 + r)
    #pragma unroll
    for (int fn = 0; fn < 4; ++fn) {
        const int col = n0 + wn * 64 + fn * 16 + lm;
        const float bv = bias[col];
        #pragma unroll
        for (int fm = 0; fm < 4; ++fm) {
            #pragma unroll
            for (int r = 0; r < 4; ++r) {
                const int row = m0 + wm * 64 + fm * 16 + kq * 4 + r;
                const float v = fmaxf(acc[fm][fn][r] + bv, 0.0f);
                const __bf16 hb = (__bf16)v;
                Chi[(size_t)row * D_HID + col] = hb;
                Clo[(size_t)row * D_HID + col] = (__bf16)(v - (float)hb);
            }
        }
    }
}

// ---------------------------------------------------------------------------
// GEMM2: enc(hi/lo) = h @ W2 + b2, plus sum(enc^2) atomic.  All-DMA staging.
// ---------------------------------------------------------------------------
__global__ __launch_bounds__(256)
void gemm2_kernel(const __bf16* __restrict__ Ahi, const __bf16* __restrict__ Alo,
                  const __bf16* __restrict__ BThi, const __bf16* __restrict__ BTlo,
                  const float* __restrict__ bias,
                  __bf16* __restrict__ Chi, __bf16* __restrict__ Clo,
                  float* __restrict__ accum)
{
    __shared__ __bf16 lds[2][4][4096];

    const int tid  = threadIdx.x;
    const int lane = tid & 63;
    const int w    = tid >> 6;
    const int wm = w >> 1, wn = w & 1;
    const int kq = lane >> 4, lm = lane & 15;
    const int m0 = blockIdx.x * 128, n0 = blockIdx.y * 128;

    f32x4 acc[4][4] = {};

    stage_pair_dma(Ahi, Alo, &lds[0][0][0], &lds[0][1][0], w, lane, m0, D_HID, 0);
    stage_pair_dma(BThi, BTlo, &lds[0][2][0], &lds[0][3][0], w, lane, n0, D_HID, 0);

    constexpr int NSTEP = D_HID / 32;
    for (int t = 0; t < NSTEP; ++t) {
        const int cur = t & 1, nxt = cur ^ 1;
        __syncthreads();
        if (t + 1 < NSTEP) {
            const int k0n = (t + 1) * 32;
            stage_pair_dma(Ahi, Alo, &lds[nxt][0][0], &lds[nxt][1][0], w, lane, m0, D_HID, k0n);
            stage_pair_dma(BThi, BTlo, &lds[nxt][2][0], &lds[nxt][3][0], w, lane, n0, D_HID, k0n);
        }
        mfma_tile(&lds[cur][0][0], &lds[cur][1][0], &lds[cur][2][0], &lds[cur][3][0],
                  wm, wn, kq, lm, acc);
    }

    float sumsq = 0.0f;
    #pragma unroll
    for (int fn = 0; fn < 4; ++fn) {
        const int col = n0 + wn * 64 + fn * 16 + lm;
        const float bv = bias[col];
        #pragma unroll
        for (int fm = 0; fm < 4; ++fm) {
            #pragma unroll
            for (int r = 0; r < 4; ++r) {
                const int row = m0 + wm * 64 + fm * 16 + kq * 4 + r;
                const float v = acc[fm][fn][r] + bv;
                sumsq = fmaf(v, v, sumsq);
                const __bf16 hb = (__bf16)v;
                Chi[(size_t)row * D_CODE_ + col] = hb;
                Clo[(size_t)row * D_CODE_ + col] = (__bf16)(v - (float)hb);
            }
        }
    }
    #pragma unroll
    for (int mk = 1; mk <= 32; mk <<= 1) sumsq += __shfl_xor(sumsq, mk);
    if (lane == 0) atomicAdd(&accum[1], sumsq);
}

// ---------------------------------------------------------------------------
// dist: dots = enc @ cb^T via MFMA; epilogue argmin + gap flagging + loss sum.
// ---------------------------------------------------------------------------
__global__ __launch_bounds__(256)
void dist_kernel(const __bf16* __restrict__ Ehi, const __bf16* __restrict__ Elo,
                 const __bf16* __restrict__ CBhi, const __bf16* __restrict__ CBlo,
                 const float* __restrict__ cbn,
                 float* __restrict__ outIdx, float* __restrict__ accum,
                 int* __restrict__ cnt, int* __restrict__ list)
{
    __shared__ __bf16 lds[2][4][4096];

    const int tid  = threadIdx.x;
    const int lane = tid & 63;
    const int w    = tid >> 6;
    const int wm = w >> 1, wn = w & 1;
    const int kq = lane >> 4, lm = lane & 15;
    const int m0 = blockIdx.x * 128;

    float cbn_l[4];
    #pragma unroll
    for (int fn = 0; fn < 4; ++fn) cbn_l[fn] = cbn[wn * 64 + fn * 16 + lm];

    f32x4 acc[4][4] = {};

    stage_pair_dma(Ehi, Elo, &lds[0][0][0], &lds[0][1][0], w, lane, m0, D_CODE_, 0);
    stage_pair_dma(CBhi, CBlo, &lds[0][2][0], &lds[0][3][0], w, lane, 0, D_CODE_, 0);

    constexpr int NSTEP = D_CODE_ / 32;
    for (int t = 0; t < NSTEP; ++t) {
        const int cur = t & 1, nxt = cur ^ 1;
        __syncthreads();
        if (t + 1 < NSTEP) {
            const int k0n = (t + 1) * 32;
            stage_pair_dma(Ehi, Elo, &lds[nxt][0][0], &lds[nxt][1][0], w, lane, m0, D_CODE_, k0n);
            stage_pair_dma(CBhi, CBlo, &lds[nxt][2][0], &lds[nxt][3][0], w, lane, 0, D_CODE_, k0n);
        }
        mfma_tile(&lds[cur][0][0], &lds[cur][1][0], &lds[cur][2][0], &lds[cur][3][0],
                  wm, wn, kq, lm, acc);
    }

    __syncthreads();
    float* eb1 = (float*)&lds[0][0][0];        // [2][128]
    float* eb2 = eb1 + 256;
    int*   eix = (int*)(eb2 + 256);

    #pragma unroll
    for (int fm = 0; fm < 4; ++fm) {
        #pragma unroll
        for (int r = 0; r < 4; ++r) {
            float b1v = 3.4e38f, b2v = 3.4e38f; int bi = 0;
            #pragma unroll
            for (int fn = 0; fn < 4; ++fn) {
                const float v = fmaf(-2.0f, acc[fm][fn][r], cbn_l[fn]);
                if (v < b1v) { b2v = b1v; b1v = v; bi = wn * 64 + fn * 16 + lm; }
                else if (v < b2v) b2v = v;
            }
            #pragma unroll
            for (int mk = 1; mk <= 8; mk <<= 1) {
                const float o1 = __shfl_xor(b1v, mk);
                const float o2 = __shfl_xor(b2v, mk);
                const int   oi = __shfl_xor(bi,  mk);
                if (o1 < b1v || (o1 == b1v && oi < bi)) { b2v = fminf(b1v, o2); b1v = o1; bi = oi; }
                else b2v = fminf(b2v, o1);
            }
            const int rl = wm * 64 + fm * 16 + kq * 4 + r;
            if (lm == 0) { eb1[wn * 128 + rl] = b1v; eb2[wn * 128 + rl] = b2v; eix[wn * 128 + rl] = bi; }
        }
    }
    __syncthreads();

    if (tid < 128) {
        const int rl = tid;
        const float a1 = eb1[rl], a2 = eb2[rl]; const int ai = eix[rl];
        const float o1 = eb1[128 + rl], o2 = eb2[128 + rl]; const int oi = eix[128 + rl];
        float B1, B2; int BI;
        if (o1 < a1 || (o1 == a1 && oi < ai)) { B1 = o1; BI = oi; B2 = fminf(a1, o2); }
        else                                  { B1 = a1; BI = ai; B2 = fminf(a2, o1); }
        outIdx[m0 + rl] = (float)BI;
        if (B2 - B1 < TAU_GAP) { const int p = atomicAdd(cnt, 1); list[p] = m0 + rl; }
        float s = B1;
        #pragma unroll
        for (int mk = 1; mk <= 32; mk <<= 1) s += __shfl_xor(s, mk);
        if (lane == 0) atomicAdd(&accum[0], s);
    }
}

// ---------------------------------------------------------------------------
// fixup: exact fp32 recompute of flagged (near-tie) rows; overwrite index.
// ---------------------------------------------------------------------------
__global__ __launch_bounds__(256)
void fixup_kernel(const float* __restrict__ x, const float* __restrict__ W1,
                  const float* __restrict__ b1, const float* __restrict__ W2,
                  const float* __restrict__ b2, const float* __restrict__ cb,
                  const float* __restrict__ cbnorm,
                  const int* __restrict__ cnt, const int* __restrict__ list,
                  float* __restrict__ outIdx)
{
    __shared__ float xr[1024];
    __shared__ float hr[512];
    __shared__ float er[256];
    __shared__ float dv[128];
    __shared__ int   di[128];

    const int tid = threadIdx.x;
    const int n = *cnt;
    for (int it = blockIdx.x; it < n; it += gridDim.x) {
        const int row = list[it];
        __syncthreads();
        #pragma unroll
        for (int i = 0; i < 4; ++i)
            xr[tid + i * 256] = x[(size_t)row * D_INK + tid + i * 256];
        __syncthreads();
        {
            const int c = tid * 2;
            float s0a = 0.f, s0b = 0.f, s1a = 0.f, s1b = 0.f;
            #pragma unroll 4
            for (int k = 0; k < D_INK; k += 2) {
                const float xv0 = xr[k], xv1 = xr[k + 1];
                const float2 w0 = *(const float2*)(W1 + (size_t)k * D_HID + c);
                const float2 w1 = *(const float2*)(W1 + (size_t)(k + 1) * D_HID + c);
                s0a = fmaf(xv0, w0.x, s0a); s1a = fmaf(xv0, w0.y, s1a);
                s0b = fmaf(xv1, w1.x, s0b); s1b = fmaf(xv1, w1.y, s1b);
            }
            hr[c]     = fmaxf(s0a + s0b + b1[c], 0.f);
            hr[c + 1] = fmaxf(s1a + s1b + b1[c + 1], 0.f);
        }
        __syncthreads();
        {
            float sa = 0.f, sb = 0.f;
            #pragma unroll 4
            for (int k = 0; k < D_HID; k += 2) {
                sa = fmaf(hr[k],     W2[(size_t)k * D_CODE_ + tid],       sa);
                sb = fmaf(hr[k + 1], W2[(size_t)(k + 1) * D_CODE_ + tid], sb);
            }
            er[tid] = sa + sb + b2[tid];
        }
        __syncthreads();
        if (tid < 128) {
            float e2a = 0.f, e2b = 0.f, da = 0.f, db = 0.f;
            const float* cr = cb + (size_t)tid * D_CODE_;
            #pragma unroll 4
            for (int k = 0; k < D_CODE_; k += 2) {
                e2a = fmaf(er[k], er[k], e2a);         e2b = fmaf(er[k + 1], er[k + 1], e2b);
                da  = fmaf(er[k], cr[k], da);          db  = fmaf(er[k + 1], cr[k + 1], db);
            }
            dv[tid] = ((e2a + e2b) - 2.0f * (da + db)) + cbnorm[tid];
            di[tid] = tid;
        }
        __syncthreads();
        for (int st = 64; st >= 1; st >>= 1) {
            if (tid < st) {
                const float a = dv[tid], b = dv[tid + st];
                const int  ib = di[tid + st];
                if (b < a || (b == a && ib < di[tid])) { dv[tid] = b; di[tid] = ib; }
            }
            __syncthreads();
        }
        if (tid == 0) outIdx[row] = (float)di[0];
    }
}

// ---------------------------------------------------------------------------
__global__ void finalize_kernel(const float* __restrict__ accum, float* __restrict__ out)
{
    const float inv = 1.0f / (32768.0f * 256.0f);
    const float loss = (accum[0] + accum[1]) * inv;   // commitment == codebook
    out[32768] = loss;
    out[32769] = loss;
    out[32770] = 1.25f * loss;
}

// ---------------------------------------------------------------------------
extern "C" void kernel_launch(void* const* d_in, const int* in_sizes, int n_in,
                              void* d_out, int out_size, void* d_ws, size_t ws_size,
                              hipStream_t stream)
{
    (void)in_sizes; (void)n_in; (void)out_size; (void)ws_size;

    const float* x  = (const float*)d_in[0];  // [32768,1024]
    const float* W1 = (const float*)d_in[1];  // [1024,512]
    const float* b1 = (const float*)d_in[2];  // [512]
    const float* W2 = (const float*)d_in[3];  // [512,256]
    const float* b2 = (const float*)d_in[4];  // [256]
    const float* cb = (const float*)d_in[5];  // [128,256]
    float* out = (float*)d_out;

    // workspace layout (bytes)
    char* ws = (char*)d_ws;
    __bf16* W1Thi = (__bf16*)(ws + 0);                    // 1 MB  [512][1024]
    __bf16* W1Tlo = (__bf16*)(ws + (1u<<20));             // 1 MB
    __bf16* W2Thi = (__bf16*)(ws + (2u<<20));             // 256 KB [256][512]
    __bf16* W2Tlo = (__bf16*)(ws + (2u<<20) + 262144);    // 256 KB
    __bf16* cbhi  = (__bf16*)(ws + (2u<<20) + 524288);    // 64 KB  [128][256]
    __bf16* cblo  = (__bf16*)(ws + (2u<<20) + 589824);    // 64 KB
    float*  cbn   = (float* )(ws + (2u<<20) + 655360);    // 512 B
    float*  accum = (float* )(ws + (2u<<20) + 655872);    // 64 B
    int*    cnt   = (int*   )(ws + (2u<<20) + 655936);    // 64 B
    int*    list  = (int*   )(ws + (2u<<20) + 656000);    // 128 KB
    __bf16* h_hi  = (__bf16*)(ws + (size_t)(4u<<20));             // 32 MB
    __bf16* h_lo  = (__bf16*)(ws + (size_t)(4u<<20) + 33554432);  // 32 MB
    __bf16* enchi = (__bf16*)(ws + (size_t)(4u<<20) + 67108864);  // 16 MB
    __bf16* enclo = (__bf16*)(ws + (size_t)(4u<<20) + 83886080);  // 16 MB

    prep_cb_kernel<<<N_CODES_, 256, 0, stream>>>(cb, cbhi, cblo, cbn, accum, cnt);
    splitT_kernel<<<dim3(D_INK / 64, D_HID / 64), 256, 0, stream>>>(W1, W1Thi, W1Tlo, D_INK, D_HID);
    splitT_kernel<<<dim3(D_HID / 64, D_CODE_ / 64), 256, 0, stream>>>(W2, W2Thi, W2Tlo, D_HID, D_CODE_);

    gemm1_kernel<<<dim3(M_ROWS / 128, D_HID / 128), 256, 0, stream>>>(
        x, W1Thi, W1Tlo, b1, h_hi, h_lo);
    gemm2_kernel<<<dim3(M_ROWS / 128, D_CODE_ / 128), 256, 0, stream>>>(
        h_hi, h_lo, W2Thi, W2Tlo, b2, enchi, enclo, accum);
    dist_kernel<<<M_ROWS / 128, 256, 0, stream>>>(
        enchi, enclo, cbhi, cblo, cbn, out, accum, cnt, list);
    fixup_kernel<<<256, 256, 0, stream>>>(x, W1, b1, W2, b2, cb, cbn, cnt, list, out);
    finalize_kernel<<<1, 1, 0, stream>>>(accum, out);
}